// Round 1
// 72.399 us; speedup vs baseline: 1.0068x; 1.0068x over previous
//
#include <hip/hip_runtime.h>

// B=131072 points (D=16 fp32), K=256 centers. Out (fp32): [B] argmin idx ++ [B,16] offsets.
//
// Round-12: TLP. Evidence r2-r11: kernel ~19-25us invariant to k-loop
// formulation, gather source (global vs LDS: -1.3us bench vs -7 predicted),
// and launch_bounds. Issue model says the k-loop floor is ~5.3us -> the
// limiter is NOT ALU issue. The one axis never actually moved: resident
// waves. Grid was always 1024 blocks x 4 waves = 16 waves/CU (4/SIMD, 50%).
// launch_bounds experiments can't raise that when the grid supplies too few
// waves. This round: block=512 = 8 waves, K-split 8 (KC=32), grid still
// 1024 -> 4 blocks/CU x 8 waves = 32 waves/CU (HW max, 8/SIMD). Per-wave
// k-loop halves -> finer interleave across the barrier-split phases; SMEM
// lgkmcnt(0) drains, LDS latency, and the HBM bookends get 2x the waves to
// hide under. launch_bounds(512,8) caps VGPR at 64 (live set ~55-60).
//
// Arithmetic per point is identical to r11: score = c2[k] - 2*x.c via
// v_pk_fma_f32 (2 pts/lane), strict < + ascending k => lowest-k ties,
// matching jnp.argmin. absmax 0 expected.

constexpr int Bn = 131072;
constexpr int Kn = 256;
constexpr int Dn = 16;
constexpr int PTS = 128;      // points per block (2 per lane per wave-pair layout)
constexpr int NW = 8;         // waves per block == K chunks
constexpr int KC = Kn / NW;   // 32 centers per wave

typedef float v2f __attribute__((ext_vector_type(2)));

__global__ __launch_bounds__(512, 8) void kmeans_kernel(
    const float* __restrict__ traj, const float* __restrict__ centers,
    float* __restrict__ out) {
  __shared__ float c2s[Kn];
  __shared__ float4 cs4[Kn][4];     // centers copy for the epilogue gather (16KB)
  __shared__ float sbest[NW * PTS];
  __shared__ int sbi[NW * PTS];
  __shared__ int swin[PTS];

  const int t = threadIdx.x;
  const int blk = blockIdx.x;

  // ---- Stage 1: threads 0..255 load center row t (4x float4), compute c2,
  // and stage the row into LDS for the epilogue gather. Waves 4-7 idle here
  // (they proceed to the barrier; their k-loop work starts right after).
  if (t < Kn) {
    const float4* cp = reinterpret_cast<const float4*>(centers + t * Dn);
    float4 a = cp[0], b = cp[1], c = cp[2], d = cp[3];
    float s = 0.0f;
    s = fmaf(a.x, a.x, s); s = fmaf(a.y, a.y, s);
    s = fmaf(a.z, a.z, s); s = fmaf(a.w, a.w, s);
    s = fmaf(b.x, b.x, s); s = fmaf(b.y, b.y, s);
    s = fmaf(b.z, b.z, s); s = fmaf(b.w, b.w, s);
    s = fmaf(c.x, c.x, s); s = fmaf(c.y, c.y, s);
    s = fmaf(c.z, c.z, s); s = fmaf(c.w, c.w, s);
    s = fmaf(d.x, d.x, s); s = fmaf(d.y, d.y, s);
    s = fmaf(d.z, d.z, s); s = fmaf(d.w, d.w, s);
    c2s[t] = s;
    cs4[t][0] = a; cs4[t][1] = b; cs4[t][2] = c; cs4[t][3] = d;
  }
  __syncthreads();

  const int w = __builtin_amdgcn_readfirstlane(t >> 6);  // wave id 0..7 (SGPR)
  const int l = t & 63;                                  // lane
  const int p0 = blk * PTS + l;        // this lane's point 0
  const int p1 = p0 + 64;              // this lane's point 1

  // ---- Load y = -2*x for both points, packed {pt0, pt1} per dim.
  v2f y[Dn];
  {
    const float4* xa = reinterpret_cast<const float4*>(traj + (size_t)p0 * Dn);
    const float4* xb = reinterpret_cast<const float4*>(traj + (size_t)p1 * Dn);
#pragma unroll
    for (int q = 0; q < 4; ++q) {
      float4 a = xa[q], b = xb[q];
      y[q * 4 + 0] = (v2f){-2.0f * a.x, -2.0f * b.x};
      y[q * 4 + 1] = (v2f){-2.0f * a.y, -2.0f * b.y};
      y[q * 4 + 2] = (v2f){-2.0f * a.z, -2.0f * b.z};
      y[q * 4 + 3] = (v2f){-2.0f * a.w, -2.0f * b.w};
    }
  }

  float best0 = __builtin_inff(), best1 = __builtin_inff();
  int bi0 = 0, bi1 = 0;
  const int k0 = w * KC;
#pragma unroll 4
  for (int kk = 0; kk < KC; ++kk) {
    const int k = k0 + kk;
    const float* cr = centers + k * Dn;  // wave-uniform -> s_load
    const float c2k = c2s[k];
    v2f acc = (v2f){c2k, c2k};
#pragma unroll
    for (int d = 0; d < Dn; ++d) {
      const float c = cr[d];             // SGPR; broadcast into both halves
      acc = y[d] * (v2f){c, c} + acc;    // contracts to v_pk_fma_f32
    }
    if (acc.x < best0) { best0 = acc.x; bi0 = k; }  // strict <: lowest-k ties
    if (acc.y < best1) { best1 = acc.y; bi1 = k; }
  }
  sbest[w * PTS + l] = best0;
  sbi[w * PTS + l] = bi0;
  sbest[w * PTS + 64 + l] = best1;
  sbi[w * PTS + 64 + l] = bi1;
  __syncthreads();

  // ---- Cross-wave reduction: threads 0..127, one per point. Ascending chunk
  // order + strict < keeps the lowest-k winner on exact ties.
  if (t < PTS) {
    float b0 = sbest[t];
    int i0 = sbi[t];
#pragma unroll
    for (int ww = 1; ww < NW; ++ww) {
      float b1 = sbest[ww * PTS + t];
      int i1 = sbi[ww * PTS + t];
      if (b1 < b0) { b0 = b1; i0 = i1; }
    }
    swin[t] = i0;
    out[blk * PTS + t] = (float)i0;  // idx output (fp32 buffer), coalesced
  }
  __syncthreads();

  // ---- Coalesced offset stores: 128 points x 4 quarters = 512 float4 ops,
  // exactly one per thread now. x re-read from traj is coalesced + L1-hot;
  // center quarter comes from the LDS copy (ds_read_b128 gather).
  {
    const int pb = t >> 2, q = t & 3;
    const int pt = blk * PTS + pb;
    const int win = swin[pb];
    float4 xv = reinterpret_cast<const float4*>(traj + (size_t)pt * Dn)[q];  // L1-hot
    float4 cv = cs4[win][q];                                                 // LDS gather
    float4 o = make_float4(xv.x - cv.x, xv.y - cv.y, xv.z - cv.z, xv.w - cv.w);
    reinterpret_cast<float4*>(out + Bn)[(size_t)pt * 4 + q] = o;
  }
}

extern "C" void kernel_launch(void* const* d_in, const int* in_sizes, int n_in,
                              void* d_out, int out_size, void* d_ws, size_t ws_size,
                              hipStream_t stream) {
  (void)in_sizes; (void)n_in; (void)out_size; (void)d_ws; (void)ws_size;
  const float* traj = (const float*)d_in[0];     // [131072, 16]
  const float* centers = (const float*)d_in[1];  // [256, 16]
  float* out = (float*)d_out;                    // [131072] idx ++ [131072*16] offsets
  kmeans_kernel<<<Bn / PTS, 512, 0, stream>>>(traj, centers, out);
}